// Round 9
// baseline (168.117 us; speedup 1.0000x reference)
//
#include <hip/hip_runtime.h>

// Problem constants (reference: B=16384, DIM_X=2048, K=128)
#define BB 16384
#define DD 2048
#define KK 128
#define NT 64            // DD / 32 k-steps
#define NCHK 16          // chunks of 4 k-steps
#define RPB 32           // rows per block
#define NBLK 512         // blocks (2 per CU)
#define DELTA 3e-4f      // argmax gap below which we re-resolve in fp64 (~30 sigma)
#define CHB 16384        // chunk LDS buffer bytes (32 rows x 512 B raw f32)

typedef __attribute__((ext_vector_type(8))) short  bf16x8;
typedef __attribute__((ext_vector_type(4))) float  f32x4;
typedef __attribute__((ext_vector_type(4))) unsigned int u32x4;

union V16 { u32x4 u; f32x4 f; bf16x8 s; };

__device__ __forceinline__ void gld16(const void* g, void* l) {
  __builtin_amdgcn_global_load_lds(
      (const __attribute__((address_space(1))) void*)g,
      (__attribute__((address_space(3))) void*)l, 16, 0, 0);
}

// ---------------------------------------------------------------------------
// Prep: split enc_W into bf16 hi/lo and dec_W into bf16 hi, laid out in MFMA
// B-fragment order: element ((t*8+ct)*64+l)*8+j <-> W[ct*16+(l&15)][t*32+(l>>4)*8+j]
// Also zeroes the loss/accuracy accumulators and the flag counter.
// ---------------------------------------------------------------------------
__global__ __launch_bounds__(256) void prep_kernel(
    const float* __restrict__ encW, const float* __restrict__ decW,
    unsigned short* __restrict__ wEh, unsigned short* __restrict__ wEl,
    unsigned short* __restrict__ wDh,
    float* __restrict__ out, unsigned int* __restrict__ counter)
{
  int id = blockIdx.x * 256 + threadIdx.x;           // 0 .. 65535
  if (id == 0) { *counter = 0u; out[2*BB] = 0.f; out[2*BB+1] = 0.f; }
  int sel = id >> 15;                                // 0 = enc, 1 = dec
  int idx = id & 32767;
  int l  = idx & 63;
  int ct = (idx >> 6) & 7;
  int t  = idx >> 9;
  const float* W = sel ? decW : encW;
  int col = ct * 16 + (l & 15);
  int k0  = t * 32 + ((l >> 4) << 3);
  const float* src = W + (size_t)col * DD + k0;
  V16 vh, vl;
#pragma unroll
  for (int p = 0; p < 4; ++p) {
    unsigned hu[2], lu[2];
#pragma unroll
    for (int q = 0; q < 2; ++q) {
      float f = src[p*2 + q];
      unsigned u  = __float_as_uint(f);
      unsigned rh = u + 0x7FFFu + ((u >> 16) & 1u);   // RNE to bf16
      unsigned hb = rh >> 16;
      float hf = __uint_as_float(hb << 16);
      float r  = f - hf;                               // exact residual
      unsigned ur = __float_as_uint(r);
      unsigned rl = ur + 0x7FFFu + ((ur >> 16) & 1u);
      hu[q] = hb & 0xFFFFu; lu[q] = (rl >> 16) & 0xFFFFu;
    }
    vh.u[p] = (hu[1] << 16) | hu[0];
    vl.u[p] = (lu[1] << 16) | lu[0];
  }
  if (sel == 0) {
    *(u32x4*)(wEh + (size_t)idx * 8) = vh.u;
    *(u32x4*)(wEl + (size_t)idx * 8) = vl.u;
  } else {
    *(u32x4*)(wDh + (size_t)idx * 8) = vh.u;
  }
}

// ---------------------------------------------------------------------------
// Main fused kernel: 512 blocks x 512 threads (2 blocks/CU, 16 waves/CU).
// amdgpu_waves_per_eu(4,4): pins RA to the 128-VGPR bucket -- the ~110-VGPR
// live set (12 B-frags + 4 acc + staging) fits with NO SPILLS. Round 8's 64-VGPR
// auto-target spilled (12 MB scratch writes) and wrecked the pipeline.
// Wave w: wr = w>>2 (16-row group), wc = w&3 (32-col group, 2 MFMA col-tiles).
// x staged RAW f32 via global_load_lds; 16B-block index XOR-swizzled with
// (row&7) on the GLOBAL SOURCE side (LDS dest linear) -> ds_read_b128 lands
// exactly 8 words/bank. bf16 hi/lo split on read (v_perm), shared by both
// col-tiles. B fragments global->VGPR, per-kstep double-buffered.
// Chunk = 4 ksteps; barrier = s_waitcnt vmcnt(24) (gld16 retired, 24 B-loads
// in flight) + lgkmcnt(0) + s_barrier. Load-issue order pinned by fence.
// ---------------------------------------------------------------------------
__global__ __launch_bounds__(512)
__attribute__((amdgpu_waves_per_eu(4, 4)))
void main_kernel(
    const float* __restrict__ x, const float* __restrict__ y,
    const float* __restrict__ encb, const float* __restrict__ decb,
    const unsigned short* __restrict__ wEh, const unsigned short* __restrict__ wEl,
    const unsigned short* __restrict__ wDh,
    float* __restrict__ out, unsigned int* __restrict__ counter,
    unsigned int* __restrict__ list)
{
  __shared__ __align__(16) unsigned char pool[32768];
  const int tid = threadIdx.x;
  const int w = tid >> 6, l = tid & 63;
  const int wr = w >> 2, wc = w & 3;
  const int rbase = blockIdx.x * RPB;

  // STAGE: round jj covers rows jj*16 + (tid>>5); lane writes LDS block tid&31;
  // global source block = (tid&31) ^ (row&7)  [row&7 == (tid>>5)&7]
  const float* gXs[2];
  {
    const int srow = tid >> 5, b = tid & 31;
#pragma unroll
    for (int jj = 0; jj < 2; ++jj)
      gXs[jj] = x + (size_t)(rbase + jj * 16 + srow) * DD
                  + ((b ^ (srow & 7)) << 2);
  }
  auto STAGE = [&](int buf, int c) {
#pragma unroll
    for (int jj = 0; jj < 2; ++jj)
      gld16(gXs[jj] + (size_t)c * 128, pool + buf + jj * 8192 + w * 1024);
  };

  // A-fragment LDS offsets: row R = wr*16 + (l&15); logical 16B-block
  // beta = tt*8 + (l>>4)*2 (+1); read LDS block beta ^ (R&7)
  const int rowb = (wr * 16 + (l & 15)) * 512;
  int blk0[4], blk1[4];
#pragma unroll
  for (int tt = 0; tt < 4; ++tt) {
    int beta = tt * 8 + ((l >> 4) << 1);
    blk0[tt] = ((beta    ) ^ (l & 7)) << 4;
    blk1[tt] = ((beta + 1) ^ (l & 7)) << 4;
  }

  // B fragment sources; wave covers col-tiles wc*2, wc*2+1
  const unsigned short* gE = wEh + (size_t)(wc * 2) * 512 + l * 8;
  const unsigned short* gL = wEl + (size_t)(wc * 2) * 512 + l * 8;
  const unsigned short* gD = wDh + (size_t)(wc * 2) * 512 + l * 8;

  f32x4 accE[2], accD[2];
  const f32x4 zero4 = {0.f, 0.f, 0.f, 0.f};
#pragma unroll
  for (int ct = 0; ct < 2; ++ct) { accE[ct] = zero4; accD[ct] = zero4; }

#define FENCE() asm volatile("" ::: "memory")
#define LDB(base, t, ct) (*(const bf16x8*)((base) + (size_t)(t) * 4096 + (ct) * 512))
#define LDBH(t, E0, E1, L0, L1, D0, D1) do {                         \
    int _tc = (t) > 63 ? 63 : (t);                                   \
    E0 = LDB(gE, _tc, 0); E1 = LDB(gE, _tc, 1);                      \
    L0 = LDB(gL, _tc, 0); L1 = LDB(gL, _tc, 1);                      \
    D0 = LDB(gD, _tc, 0); D1 = LDB(gD, _tc, 1);                      \
  } while (0)

#define MFMA(a, b, c) __builtin_amdgcn_mfma_f32_16x16x32_bf16(a, b, c, 0, 0, 0)
#define KSTEP(cbase, tt, E0, E1, L0, L1, D0, D1) do {                            \
    const unsigned char* ap = pool + (cbase) + rowb;                             \
    f32x4 a0 = *(const f32x4*)(ap + blk0[tt]);                                   \
    f32x4 a1 = *(const f32x4*)(ap + blk1[tt]);                                   \
    float fa[8] = {a0[0],a0[1],a0[2],a0[3],a1[0],a1[1],a1[2],a1[3]};             \
    V16 vh, vl;                                                                  \
    _Pragma("unroll")                                                            \
    for (int p = 0; p < 4; ++p) {                                                \
      unsigned u0 = __float_as_uint(fa[2*p]);                                    \
      unsigned u1 = __float_as_uint(fa[2*p+1]);                                  \
      vh.u[p] = __builtin_amdgcn_perm(u1, u0, 0x07060302u);                      \
      float r0 = fa[2*p]   - __uint_as_float(u0 & 0xFFFF0000u);                  \
      float r1 = fa[2*p+1] - __uint_as_float(u1 & 0xFFFF0000u);                  \
      vl.u[p] = __builtin_amdgcn_perm(__float_as_uint(r1),                       \
                                      __float_as_uint(r0), 0x07060302u);         \
    }                                                                            \
    bf16x8 ah = vh.s, al = vl.s;                                                 \
    accE[0] = MFMA(ah, E0, accE[0]);                                             \
    accE[1] = MFMA(ah, E1, accE[1]);                                             \
    accD[0] = MFMA(ah, D0, accD[0]);                                             \
    accD[1] = MFMA(ah, D1, accD[1]);                                             \
    accE[0] = MFMA(al, E0, accE[0]);                                             \
    accE[1] = MFMA(al, E1, accE[1]);                                             \
    accE[0] = MFMA(ah, L0, accE[0]);                                             \
    accE[1] = MFMA(ah, L1, accE[1]);                                             \
  } while (0)

  bf16x8 Ae0, Ae1, Al0, Al1, Ad0, Ad1;   // set A (even ksteps)
  bf16x8 Be0, Be1, Bl0, Bl1, Bd0, Bd1;   // set B (odd ksteps)

  // prologue: chunk 0 x -> buf0 (DMA, oldest in vm queue); B kstep0 -> set A
  STAGE(0, 0);
  FENCE();
  LDBH(0, Ae0, Ae1, Al0, Al1, Ad0, Ad1);
  asm volatile("s_waitcnt vmcnt(6) lgkmcnt(0)" ::: "memory");
  __builtin_amdgcn_s_barrier();

  for (int c = 0; c < NCHK; ++c) {
    const int cb = (c & 1) * CHB;
    if (c + 1 < NCHK) STAGE(cb ^ CHB, c + 1);   // 2 gld16, oldest this chunk
    FENCE();                                     // pin issue order for vmcnt count
    LDBH(4*c + 1, Be0, Be1, Bl0, Bl1, Bd0, Bd1);
    __builtin_amdgcn_s_setprio(1);
    KSTEP(cb, 0, Ae0, Ae1, Al0, Al1, Ad0, Ad1);
    __builtin_amdgcn_s_setprio(0);
    LDBH(4*c + 2, Ae0, Ae1, Al0, Al1, Ad0, Ad1);
    __builtin_amdgcn_s_setprio(1);
    KSTEP(cb, 1, Be0, Be1, Bl0, Bl1, Bd0, Bd1);
    __builtin_amdgcn_s_setprio(0);
    LDBH(4*c + 3, Be0, Be1, Bl0, Bl1, Bd0, Bd1);
    __builtin_amdgcn_s_setprio(1);
    KSTEP(cb, 2, Ae0, Ae1, Al0, Al1, Ad0, Ad1);
    __builtin_amdgcn_s_setprio(0);
    LDBH(4*c + 4, Ae0, Ae1, Al0, Al1, Ad0, Ad1);  // next chunk kstep0
    __builtin_amdgcn_s_setprio(1);
    KSTEP(cb, 3, Be0, Be1, Bl0, Bl1, Bd0, Bd1);
    __builtin_amdgcn_s_setprio(0);
    // counted barrier: retires the 2 gld16 (oldest), leaves 24 B-loads in flight
    asm volatile("s_waitcnt vmcnt(24) lgkmcnt(0)" ::: "memory");
    __builtin_amdgcn_s_barrier();
  }
#undef LDBH
#undef KSTEP
#undef LDB
#undef MFMA
#undef FENCE

  // ---------------- epilogue (overlays the staging pool) ----------------
  float* sT  = (float*)pool;                  // [32][132] dec-GEMM results
  float* sm1 = (float*)(pool + 16896);        // [32][4] top-1
  float* sm2 = (float*)(pool + 17408);        // [32][4] top-2
  int*   si1 = (int*)  (pool + 17920);        // [32][4] argmax col

  {
    const int q = l >> 4, cc = l & 15;
#pragma unroll
    for (int ct = 0; ct < 2; ++ct) {
      const int col = wc * 32 + ct * 16 + cc;
#pragma unroll
      for (int i = 0; i < 4; ++i)
        sT[(wr * 16 + q * 4 + i) * 132 + col] = accD[ct][i];
    }
    const int col0 = wc * 32 + cc, col1 = col0 + 16;
    const float b0 = encb[col0], b1 = encb[col1];
    float m1v[4], m2v[4]; int i1v[4];
#pragma unroll
    for (int i = 0; i < 4; ++i) {
      float v0 = accE[0][i] + b0;
      float v1 = accE[1][i] + b1;
      if (v0 >= v1) { m1v[i] = v0; m2v[i] = v1; i1v[i] = col0; }
      else          { m1v[i] = v1; m2v[i] = v0; i1v[i] = col1; }
    }
#pragma unroll
    for (int d = 1; d < 16; d <<= 1) {
#pragma unroll
      for (int i = 0; i < 4; ++i) {
        float om1 = __shfl_xor(m1v[i], d);
        float om2 = __shfl_xor(m2v[i], d);
        int   oi  = __shfl_xor(i1v[i], d);
        if (om1 > m1v[i] || (om1 == m1v[i] && oi < i1v[i])) {
          m2v[i] = fmaxf(m1v[i], om2); m1v[i] = om1; i1v[i] = oi;
        } else {
          m2v[i] = fmaxf(m2v[i], om1);
        }
      }
    }
    if (cc == 0) {
#pragma unroll
      for (int i = 0; i < 4; ++i) {
        const int row = wr * 16 + q * 4 + i;
        sm1[row * 4 + wc] = m1v[i];
        sm2[row * 4 + wc] = m2v[i];
        si1[row * 4 + wc] = i1v[i];
      }
    }
  }
  __syncthreads();

  float lossAcc = 0.f, accAcc = 0.f;
  if (tid < RPB) {
    const int row = tid, R = rbase + row;
    float m1 = -3.4e38f, m2 = -3.4e38f; int i1 = 0;
#pragma unroll
    for (int g = 0; g < 4; ++g) {
      float a1 = sm1[row * 4 + g], a2 = sm2[row * 4 + g];
      int ai = si1[row * 4 + g];
      if (a1 > m1) { m2 = fmaxf(m1, a2); m1 = a1; i1 = ai; }
      else         { m2 = fmaxf(m2, a1); }
    }
    float yh = sT[row * 132 + i1] + decb[i1];
    out[R]      = yh;
    out[BB + R] = (float)i1;
    if (m1 - m2 < DELTA) {                     // near-tie: fp64 re-resolve later
      unsigned p = atomicAdd(counter, 1u);
      if (p < 65536u) list[p] = (unsigned)R;
    }
    float yv = y[R];
    float d  = yh - yv;
    lossAcc = d * d;
    float sg = (yh > 0.f) ? 1.f : ((yh < 0.f) ? -1.f : 0.f);
    accAcc = (sg == yv) ? 1.f : 0.f;
  }
#pragma unroll
  for (int d = 1; d < 64; d <<= 1) {
    lossAcc += __shfl_xor(lossAcc, d);
    accAcc  += __shfl_xor(accAcc, d);
  }
  if (tid == 0) {
    atomicAdd(&out[2*BB],     lossAcc * (1.f / BB));
    atomicAdd(&out[2*BB + 1], accAcc  * (1.f / BB));
  }
}

// ---------------------------------------------------------------------------
// Fixup: fp64 re-resolution of flagged near-tie rows. Coalesced + wave-parallel:
// x row staged in LDS; wave v computes cols 32v..32v+31, lanes stripe k in
// float4 (64-lane x 16B coalesced); fp64 FMA chains + shfl reduce.
// ---------------------------------------------------------------------------
__global__ __launch_bounds__(256) void fixup_kernel(
    const float* __restrict__ x, const float* __restrict__ y,
    const float* __restrict__ encW, const float* __restrict__ encb,
    const float* __restrict__ decW, const float* __restrict__ decb,
    float* __restrict__ out,
    const unsigned int* __restrict__ counter, const unsigned int* __restrict__ list)
{
  __shared__ __align__(16) float sx[2048];
  __shared__ double scol[128];
  __shared__ double sp[256];
  __shared__ int ksh;
  int n = (int)*counter;
  if (n > 65536) n = 65536;
  const int tid = threadIdx.x;
  const int wv = tid >> 6, ln = tid & 63;
  for (int e = blockIdx.x; e < n; e += gridDim.x) {
    const int R = (int)list[e];
    const float* xr = x + (size_t)R * DD;
    *(f32x4*)(sx + tid * 8)     = *(const f32x4*)(xr + tid * 8);
    *(f32x4*)(sx + tid * 8 + 4) = *(const f32x4*)(xr + tid * 8 + 4);
    __syncthreads();
    for (int ci = 0; ci < 32; ++ci) {
      const int col = wv * 32 + ci;
      const float* wp = encW + (size_t)col * DD;
      double s0 = 0., s1 = 0., s2 = 0., s3 = 0.;
#pragma unroll
      for (int j = 0; j < 8; ++j) {
        const int k = (j * 64 + ln) * 4;
        f32x4 wv4 = *(const f32x4*)(wp + k);
        f32x4 xv4 = *(const f32x4*)(sx + k);
        s0 = fma((double)xv4[0], (double)wv4[0], s0);
        s1 = fma((double)xv4[1], (double)wv4[1], s1);
        s2 = fma((double)xv4[2], (double)wv4[2], s2);
        s3 = fma((double)xv4[3], (double)wv4[3], s3);
      }
      double s = (s0 + s1) + (s2 + s3);
#pragma unroll
      for (int d = 1; d < 64; d <<= 1) s += __shfl_xor(s, d);
      if (ln == 0) scol[col] = s + (double)encb[col];
    }
    __syncthreads();
    if (tid == 0) {
      double best = scol[0]; int bi = 0;
      for (int c = 1; c < 128; ++c) if (scol[c] > best) { best = scol[c]; bi = c; }
      ksh = bi;
    }
    __syncthreads();
    const int kstar = ksh;
    {
      const float* dr = decW + (size_t)kstar * DD;
      const int k0 = tid * 8;
      double s = 0.;
#pragma unroll
      for (int j = 0; j < 8; ++j)
        s = fma((double)sx[k0 + j], (double)dr[k0 + j], s);
      sp[tid] = s;
    }
    __syncthreads();
    for (int st = 128; st > 0; st >>= 1) {
      if (tid < st) sp[tid] += sp[tid + st];
      __syncthreads();
    }
    if (tid == 0) {
      float yh = (float)(sp[0] + (double)decb[kstar]);
      float yv = y[R];
      float old = out[R];
      float dn = yh - yv, dol = old - yv;
      atomicAdd(&out[2*BB], (dn*dn - dol*dol) * (1.f / BB));
      float sgn = (yh  > 0.f) ? 1.f : ((yh  < 0.f) ? -1.f : 0.f);
      float sgo = (old > 0.f) ? 1.f : ((old < 0.f) ? -1.f : 0.f);
      float mn = (sgn == yv) ? 1.f : 0.f;
      float mo = (sgo == yv) ? 1.f : 0.f;
      atomicAdd(&out[2*BB + 1], (mn - mo) * (1.f / BB));
      out[R]      = yh;
      out[BB + R] = (float)kstar;
    }
    __syncthreads();
  }
}

extern "C" void kernel_launch(void* const* d_in, const int* in_sizes, int n_in,
                              void* d_out, int out_size, void* d_ws, size_t ws_size,
                              hipStream_t stream)
{
  const float* x    = (const float*)d_in[0];
  const float* y    = (const float*)d_in[1];
  // d_in[2] = z (unused by the reference computation)
  const float* encW = (const float*)d_in[3];
  const float* encb = (const float*)d_in[4];
  const float* decW = (const float*)d_in[5];   // [1,128,2048] -> row-major [128][2048]
  const float* decb = (const float*)d_in[6];
  float* out = (float*)d_out;

  unsigned char* ws = (unsigned char*)d_ws;
  unsigned short* wEh = (unsigned short*)ws;
  unsigned short* wEl = (unsigned short*)(ws + 524288);
  unsigned short* wDh = (unsigned short*)(ws + 1048576);
  unsigned int* counter = (unsigned int*)(ws + 1572864);
  unsigned int* list    = (unsigned int*)(ws + 1572864 + 16);

  prep_kernel<<<256, 256, 0, stream>>>(encW, decW, wEh, wEl, wDh, out, counter);
  main_kernel<<<NBLK, 512, 0, stream>>>(x, y, encb, decb, wEh, wEl, wDh,
                                        out, counter, list);
  fixup_kernel<<<512, 256, 0, stream>>>(x, y, encW, encb, decW, decb,
                                        out, counter, list);
}

// Round 10
// 167.324 us; speedup vs baseline: 1.0047x; 1.0047x over previous
//
#include <hip/hip_runtime.h>

// Problem constants (reference: B=16384, DIM_X=2048, K=128)
#define BB 16384
#define DD 2048
#define KK 128
#define NT 64            // DD / 32 k-steps
#define NCHK 16          // chunks of 4 k-steps
#define RPB 32           // rows per block
#define NBLK 512         // blocks (2 per CU)
#define DELTA 3e-4f      // argmax gap below which we re-resolve in fp64 (~30 sigma)
#define CHB 16384        // chunk LDS buffer bytes (32 rows x 512 B raw f32)

typedef __attribute__((ext_vector_type(8))) short  bf16x8;
typedef __attribute__((ext_vector_type(4))) float  f32x4;
typedef __attribute__((ext_vector_type(4))) unsigned int u32x4;

union V16 { u32x4 u; f32x4 f; bf16x8 s; };

__device__ __forceinline__ void gld16(const void* g, void* l) {
  __builtin_amdgcn_global_load_lds(
      (const __attribute__((address_space(1))) void*)g,
      (__attribute__((address_space(3))) void*)l, 16, 0, 0);
}

// ---------------------------------------------------------------------------
// Prep: split enc_W into bf16 hi/lo and dec_W into bf16 hi, laid out in MFMA
// B-fragment order: element ((t*8+ct)*64+l)*8+j <-> W[ct*16+(l&15)][t*32+(l>>4)*8+j]
// Also zeroes the loss/accuracy accumulators and the flag counter.
// ---------------------------------------------------------------------------
__global__ __launch_bounds__(256) void prep_kernel(
    const float* __restrict__ encW, const float* __restrict__ decW,
    unsigned short* __restrict__ wEh, unsigned short* __restrict__ wEl,
    unsigned short* __restrict__ wDh,
    float* __restrict__ out, unsigned int* __restrict__ counter)
{
  int id = blockIdx.x * 256 + threadIdx.x;           // 0 .. 65535
  if (id == 0) { *counter = 0u; out[2*BB] = 0.f; out[2*BB+1] = 0.f; }
  int sel = id >> 15;                                // 0 = enc, 1 = dec
  int idx = id & 32767;
  int l  = idx & 63;
  int ct = (idx >> 6) & 7;
  int t  = idx >> 9;
  const float* W = sel ? decW : encW;
  int col = ct * 16 + (l & 15);
  int k0  = t * 32 + ((l >> 4) << 3);
  const float* src = W + (size_t)col * DD + k0;
  V16 vh, vl;
#pragma unroll
  for (int p = 0; p < 4; ++p) {
    unsigned hu[2], lu[2];
#pragma unroll
    for (int q = 0; q < 2; ++q) {
      float f = src[p*2 + q];
      unsigned u  = __float_as_uint(f);
      unsigned rh = u + 0x7FFFu + ((u >> 16) & 1u);   // RNE to bf16
      unsigned hb = rh >> 16;
      float hf = __uint_as_float(hb << 16);
      float r  = f - hf;                               // exact residual
      unsigned ur = __float_as_uint(r);
      unsigned rl = ur + 0x7FFFu + ((ur >> 16) & 1u);
      hu[q] = hb & 0xFFFFu; lu[q] = (rl >> 16) & 0xFFFFu;
    }
    vh.u[p] = (hu[1] << 16) | hu[0];
    vl.u[p] = (lu[1] << 16) | lu[0];
  }
  if (sel == 0) {
    *(u32x4*)(wEh + (size_t)idx * 8) = vh.u;
    *(u32x4*)(wEl + (size_t)idx * 8) = vl.u;
  } else {
    *(u32x4*)(wDh + (size_t)idx * 8) = vh.u;
  }
}

// ---------------------------------------------------------------------------
// Main fused kernel: 512 blocks x 512 threads (2 blocks/CU, 16 waves/CU).
// LDS deliberately padded to 61440 B: 160KB/CU / 60KB = 2 blocks/CU, so the
// backend's occupancy-derived VGPR budget is 128 (4 waves/EU), not 64 -- the
// ~80-reg live set (12 B-frags + acc + addressing) then fits with NO SPILLS.
// (Rounds 8/9: 32KB LDS -> 4-block occupancy bound -> 64-VGPR budget -> 12MB
// scratch writes in the K-loop. waves_per_eu/launch_bounds hints were ignored.)
// Wave w: wr = w>>2 (16-row group), wc = w&3 (32-col group, 2 MFMA col-tiles).
// x staged RAW f32 via global_load_lds; 16B-block index XOR-swizzled with
// (row&7) on the GLOBAL SOURCE side (LDS dest linear) -> ds_read_b128 lands
// exactly 8 words/bank. bf16 hi/lo split on read (v_perm), shared by both
// col-tiles. B fragments global->VGPR, per-kstep double-buffered.
// Chunk = 4 ksteps; barrier = s_waitcnt vmcnt(24) (gld16 retired, 24 B-loads
// in flight) + lgkmcnt(0) + s_barrier. Load-issue order pinned by fence.
// ---------------------------------------------------------------------------
__global__ __launch_bounds__(512)
void main_kernel(
    const float* __restrict__ x, const float* __restrict__ y,
    const float* __restrict__ encb, const float* __restrict__ decb,
    const unsigned short* __restrict__ wEh, const unsigned short* __restrict__ wEl,
    const unsigned short* __restrict__ wDh,
    float* __restrict__ out, unsigned int* __restrict__ counter,
    unsigned int* __restrict__ list)
{
  __shared__ __align__(16) unsigned char pool[61440];   // occupancy limiter: 2 blocks/CU
  const int tid = threadIdx.x;
  const int w = tid >> 6, l = tid & 63;
  const int wr = w >> 2, wc = w & 3;
  const int rbase = blockIdx.x * RPB;

  // STAGE: round jj covers rows jj*16 + (tid>>5); lane writes LDS block tid&31;
  // global source block = (tid&31) ^ (row&7)  [row&7 == (tid>>5)&7]
  const float* gXs[2];
  {
    const int srow = tid >> 5, b = tid & 31;
#pragma unroll
    for (int jj = 0; jj < 2; ++jj)
      gXs[jj] = x + (size_t)(rbase + jj * 16 + srow) * DD
                  + ((b ^ (srow & 7)) << 2);
  }
  auto STAGE = [&](int buf, int c) {
#pragma unroll
    for (int jj = 0; jj < 2; ++jj)
      gld16(gXs[jj] + (size_t)c * 128, pool + buf + jj * 8192 + w * 1024);
  };

  // A-fragment LDS offsets: row R = wr*16 + (l&15); logical 16B-block
  // beta = tt*8 + (l>>4)*2 (+1); read LDS block beta ^ (R&7)
  const int rowb = (wr * 16 + (l & 15)) * 512;
  int blk0[4], blk1[4];
#pragma unroll
  for (int tt = 0; tt < 4; ++tt) {
    int beta = tt * 8 + ((l >> 4) << 1);
    blk0[tt] = ((beta    ) ^ (l & 7)) << 4;
    blk1[tt] = ((beta + 1) ^ (l & 7)) << 4;
  }

  // B fragment sources; wave covers col-tiles wc*2, wc*2+1
  const unsigned short* gE = wEh + (size_t)(wc * 2) * 512 + l * 8;
  const unsigned short* gL = wEl + (size_t)(wc * 2) * 512 + l * 8;
  const unsigned short* gD = wDh + (size_t)(wc * 2) * 512 + l * 8;

  f32x4 accE[2], accD[2];
  const f32x4 zero4 = {0.f, 0.f, 0.f, 0.f};
#pragma unroll
  for (int ct = 0; ct < 2; ++ct) { accE[ct] = zero4; accD[ct] = zero4; }

#define FENCE() asm volatile("" ::: "memory")
#define LDB(base, t, ct) (*(const bf16x8*)((base) + (size_t)(t) * 4096 + (ct) * 512))
#define LDBH(t, E0, E1, L0, L1, D0, D1) do {                         \
    int _tc = (t) > 63 ? 63 : (t);                                   \
    E0 = LDB(gE, _tc, 0); E1 = LDB(gE, _tc, 1);                      \
    L0 = LDB(gL, _tc, 0); L1 = LDB(gL, _tc, 1);                      \
    D0 = LDB(gD, _tc, 0); D1 = LDB(gD, _tc, 1);                      \
  } while (0)

#define MFMA(a, b, c) __builtin_amdgcn_mfma_f32_16x16x32_bf16(a, b, c, 0, 0, 0)
#define KSTEP(cbase, tt, E0, E1, L0, L1, D0, D1) do {                            \
    const unsigned char* ap = pool + (cbase) + rowb;                             \
    f32x4 a0 = *(const f32x4*)(ap + blk0[tt]);                                   \
    f32x4 a1 = *(const f32x4*)(ap + blk1[tt]);                                   \
    float fa[8] = {a0[0],a0[1],a0[2],a0[3],a1[0],a1[1],a1[2],a1[3]};             \
    V16 vh, vl;                                                                  \
    _Pragma("unroll")                                                            \
    for (int p = 0; p < 4; ++p) {                                                \
      unsigned u0 = __float_as_uint(fa[2*p]);                                    \
      unsigned u1 = __float_as_uint(fa[2*p+1]);                                  \
      vh.u[p] = __builtin_amdgcn_perm(u1, u0, 0x07060302u);                      \
      float r0 = fa[2*p]   - __uint_as_float(u0 & 0xFFFF0000u);                  \
      float r1 = fa[2*p+1] - __uint_as_float(u1 & 0xFFFF0000u);                  \
      vl.u[p] = __builtin_amdgcn_perm(__float_as_uint(r1),                       \
                                      __float_as_uint(r0), 0x07060302u);         \
    }                                                                            \
    bf16x8 ah = vh.s, al = vl.s;                                                 \
    accE[0] = MFMA(ah, E0, accE[0]);                                             \
    accE[1] = MFMA(ah, E1, accE[1]);                                             \
    accD[0] = MFMA(ah, D0, accD[0]);                                             \
    accD[1] = MFMA(ah, D1, accD[1]);                                             \
    accE[0] = MFMA(al, E0, accE[0]);                                             \
    accE[1] = MFMA(al, E1, accE[1]);                                             \
    accE[0] = MFMA(ah, L0, accE[0]);                                             \
    accE[1] = MFMA(ah, L1, accE[1]);                                             \
  } while (0)

  bf16x8 Ae0, Ae1, Al0, Al1, Ad0, Ad1;   // set A (even ksteps)
  bf16x8 Be0, Be1, Bl0, Bl1, Bd0, Bd1;   // set B (odd ksteps)

  // prologue: chunk 0 x -> buf0 (DMA, oldest in vm queue); B kstep0 -> set A
  STAGE(0, 0);
  FENCE();
  LDBH(0, Ae0, Ae1, Al0, Al1, Ad0, Ad1);
  asm volatile("s_waitcnt vmcnt(6) lgkmcnt(0)" ::: "memory");
  __builtin_amdgcn_s_barrier();

  for (int c = 0; c < NCHK; ++c) {
    const int cb = (c & 1) * CHB;
    if (c + 1 < NCHK) STAGE(cb ^ CHB, c + 1);   // 2 gld16, oldest this chunk
    FENCE();                                     // pin issue order for vmcnt count
    LDBH(4*c + 1, Be0, Be1, Bl0, Bl1, Bd0, Bd1);
    __builtin_amdgcn_s_setprio(1);
    KSTEP(cb, 0, Ae0, Ae1, Al0, Al1, Ad0, Ad1);
    __builtin_amdgcn_s_setprio(0);
    LDBH(4*c + 2, Ae0, Ae1, Al0, Al1, Ad0, Ad1);
    __builtin_amdgcn_s_setprio(1);
    KSTEP(cb, 1, Be0, Be1, Bl0, Bl1, Bd0, Bd1);
    __builtin_amdgcn_s_setprio(0);
    LDBH(4*c + 3, Be0, Be1, Bl0, Bl1, Bd0, Bd1);
    __builtin_amdgcn_s_setprio(1);
    KSTEP(cb, 2, Ae0, Ae1, Al0, Al1, Ad0, Ad1);
    __builtin_amdgcn_s_setprio(0);
    LDBH(4*c + 4, Ae0, Ae1, Al0, Al1, Ad0, Ad1);  // next chunk kstep0
    __builtin_amdgcn_s_setprio(1);
    KSTEP(cb, 3, Be0, Be1, Bl0, Bl1, Bd0, Bd1);
    __builtin_amdgcn_s_setprio(0);
    // counted barrier: retires the 2 gld16 (oldest), leaves 24 B-loads in flight
    asm volatile("s_waitcnt vmcnt(24) lgkmcnt(0)" ::: "memory");
    __builtin_amdgcn_s_barrier();
  }
#undef LDBH
#undef KSTEP
#undef LDB
#undef MFMA
#undef FENCE

  // ---------------- epilogue (overlays the staging pool) ----------------
  float* sT  = (float*)pool;                  // [32][132] dec-GEMM results
  float* sm1 = (float*)(pool + 16896);        // [32][4] top-1
  float* sm2 = (float*)(pool + 17408);        // [32][4] top-2
  int*   si1 = (int*)  (pool + 17920);        // [32][4] argmax col

  {
    const int q = l >> 4, cc = l & 15;
#pragma unroll
    for (int ct = 0; ct < 2; ++ct) {
      const int col = wc * 32 + ct * 16 + cc;
#pragma unroll
      for (int i = 0; i < 4; ++i)
        sT[(wr * 16 + q * 4 + i) * 132 + col] = accD[ct][i];
    }
    const int col0 = wc * 32 + cc, col1 = col0 + 16;
    const float b0 = encb[col0], b1 = encb[col1];
    float m1v[4], m2v[4]; int i1v[4];
#pragma unroll
    for (int i = 0; i < 4; ++i) {
      float v0 = accE[0][i] + b0;
      float v1 = accE[1][i] + b1;
      if (v0 >= v1) { m1v[i] = v0; m2v[i] = v1; i1v[i] = col0; }
      else          { m1v[i] = v1; m2v[i] = v0; i1v[i] = col1; }
    }
#pragma unroll
    for (int d = 1; d < 16; d <<= 1) {
#pragma unroll
      for (int i = 0; i < 4; ++i) {
        float om1 = __shfl_xor(m1v[i], d);
        float om2 = __shfl_xor(m2v[i], d);
        int   oi  = __shfl_xor(i1v[i], d);
        if (om1 > m1v[i] || (om1 == m1v[i] && oi < i1v[i])) {
          m2v[i] = fmaxf(m1v[i], om2); m1v[i] = om1; i1v[i] = oi;
        } else {
          m2v[i] = fmaxf(m2v[i], om1);
        }
      }
    }
    if (cc == 0) {
#pragma unroll
      for (int i = 0; i < 4; ++i) {
        const int row = wr * 16 + q * 4 + i;
        sm1[row * 4 + wc] = m1v[i];
        sm2[row * 4 + wc] = m2v[i];
        si1[row * 4 + wc] = i1v[i];
      }
    }
  }
  __syncthreads();

  float lossAcc = 0.f, accAcc = 0.f;
  if (tid < RPB) {
    const int row = tid, R = rbase + row;
    float m1 = -3.4e38f, m2 = -3.4e38f; int i1 = 0;
#pragma unroll
    for (int g = 0; g < 4; ++g) {
      float a1 = sm1[row * 4 + g], a2 = sm2[row * 4 + g];
      int ai = si1[row * 4 + g];
      if (a1 > m1) { m2 = fmaxf(m1, a2); m1 = a1; i1 = ai; }
      else         { m2 = fmaxf(m2, a1); }
    }
    float yh = sT[row * 132 + i1] + decb[i1];
    out[R]      = yh;
    out[BB + R] = (float)i1;
    if (m1 - m2 < DELTA) {                     // near-tie: fp64 re-resolve later
      unsigned p = atomicAdd(counter, 1u);
      if (p < 65536u) list[p] = (unsigned)R;
    }
    float yv = y[R];
    float d  = yh - yv;
    lossAcc = d * d;
    float sg = (yh > 0.f) ? 1.f : ((yh < 0.f) ? -1.f : 0.f);
    accAcc = (sg == yv) ? 1.f : 0.f;
  }
#pragma unroll
  for (int d = 1; d < 64; d <<= 1) {
    lossAcc += __shfl_xor(lossAcc, d);
    accAcc  += __shfl_xor(accAcc, d);
  }
  if (tid == 0) {
    atomicAdd(&out[2*BB],     lossAcc * (1.f / BB));
    atomicAdd(&out[2*BB + 1], accAcc  * (1.f / BB));
  }
}

// ---------------------------------------------------------------------------
// Fixup: fp64 re-resolution of flagged near-tie rows. Coalesced + wave-parallel:
// x row staged in LDS; wave v computes cols 32v..32v+31, lanes stripe k in
// float4 (64-lane x 16B coalesced); fp64 FMA chains + shfl reduce.
// ---------------------------------------------------------------------------
__global__ __launch_bounds__(256) void fixup_kernel(
    const float* __restrict__ x, const float* __restrict__ y,
    const float* __restrict__ encW, const float* __restrict__ encb,
    const float* __restrict__ decW, const float* __restrict__ decb,
    float* __restrict__ out,
    const unsigned int* __restrict__ counter, const unsigned int* __restrict__ list)
{
  __shared__ __align__(16) float sx[2048];
  __shared__ double scol[128];
  __shared__ double sp[256];
  __shared__ int ksh;
  int n = (int)*counter;
  if (n > 65536) n = 65536;
  const int tid = threadIdx.x;
  const int wv = tid >> 6, ln = tid & 63;
  for (int e = blockIdx.x; e < n; e += gridDim.x) {
    const int R = (int)list[e];
    const float* xr = x + (size_t)R * DD;
    *(f32x4*)(sx + tid * 8)     = *(const f32x4*)(xr + tid * 8);
    *(f32x4*)(sx + tid * 8 + 4) = *(const f32x4*)(xr + tid * 8 + 4);
    __syncthreads();
    for (int ci = 0; ci < 32; ++ci) {
      const int col = wv * 32 + ci;
      const float* wp = encW + (size_t)col * DD;
      double s0 = 0., s1 = 0., s2 = 0., s3 = 0.;
#pragma unroll
      for (int j = 0; j < 8; ++j) {
        const int k = (j * 64 + ln) * 4;
        f32x4 wv4 = *(const f32x4*)(wp + k);
        f32x4 xv4 = *(const f32x4*)(sx + k);
        s0 = fma((double)xv4[0], (double)wv4[0], s0);
        s1 = fma((double)xv4[1], (double)wv4[1], s1);
        s2 = fma((double)xv4[2], (double)wv4[2], s2);
        s3 = fma((double)xv4[3], (double)wv4[3], s3);
      }
      double s = (s0 + s1) + (s2 + s3);
#pragma unroll
      for (int d = 1; d < 64; d <<= 1) s += __shfl_xor(s, d);
      if (ln == 0) scol[col] = s + (double)encb[col];
    }
    __syncthreads();
    if (tid == 0) {
      double best = scol[0]; int bi = 0;
      for (int c = 1; c < 128; ++c) if (scol[c] > best) { best = scol[c]; bi = c; }
      ksh = bi;
    }
    __syncthreads();
    const int kstar = ksh;
    {
      const float* dr = decW + (size_t)kstar * DD;
      const int k0 = tid * 8;
      double s = 0.;
#pragma unroll
      for (int j = 0; j < 8; ++j)
        s = fma((double)sx[k0 + j], (double)dr[k0 + j], s);
      sp[tid] = s;
    }
    __syncthreads();
    for (int st = 128; st > 0; st >>= 1) {
      if (tid < st) sp[tid] += sp[tid + st];
      __syncthreads();
    }
    if (tid == 0) {
      float yh = (float)(sp[0] + (double)decb[kstar]);
      float yv = y[R];
      float old = out[R];
      float dn = yh - yv, dol = old - yv;
      atomicAdd(&out[2*BB], (dn*dn - dol*dol) * (1.f / BB));
      float sgn = (yh  > 0.f) ? 1.f : ((yh  < 0.f) ? -1.f : 0.f);
      float sgo = (old > 0.f) ? 1.f : ((old < 0.f) ? -1.f : 0.f);
      float mn = (sgn == yv) ? 1.f : 0.f;
      float mo = (sgo == yv) ? 1.f : 0.f;
      atomicAdd(&out[2*BB + 1], (mn - mo) * (1.f / BB));
      out[R]      = yh;
      out[BB + R] = (float)kstar;
    }
    __syncthreads();
  }
}

extern "C" void kernel_launch(void* const* d_in, const int* in_sizes, int n_in,
                              void* d_out, int out_size, void* d_ws, size_t ws_size,
                              hipStream_t stream)
{
  const float* x    = (const float*)d_in[0];
  const float* y    = (const float*)d_in[1];
  // d_in[2] = z (unused by the reference computation)
  const float* encW = (const float*)d_in[3];
  const float* encb = (const float*)d_in[4];
  const float* decW = (const float*)d_in[5];   // [1,128,2048] -> row-major [128][2048]
  const float* decb = (const float*)d_in[6];
  float* out = (float*)d_out;

  unsigned char* ws = (unsigned char*)d_ws;
  unsigned short* wEh = (unsigned short*)ws;
  unsigned short* wEl = (unsigned short*)(ws + 524288);
  unsigned short* wDh = (unsigned short*)(ws + 1048576);
  unsigned int* counter = (unsigned int*)(ws + 1572864);
  unsigned int* list    = (unsigned int*)(ws + 1572864 + 16);

  prep_kernel<<<256, 256, 0, stream>>>(encW, decW, wEh, wEl, wDh, out, counter);
  main_kernel<<<NBLK, 512, 0, stream>>>(x, y, encb, decb, wEh, wEl, wDh,
                                        out, counter, list);
  fixup_kernel<<<512, 256, 0, stream>>>(x, y, encW, encb, decW, decb,
                                        out, counter, list);
}

// Round 11
// 85.463 us; speedup vs baseline: 1.9671x; 1.9579x over previous
//
#include <hip/hip_runtime.h>

// Problem constants (reference: B=16384, DIM_X=2048, K=128)
#define BB 16384
#define DD 2048
#define KK 128
#define NT 64            // DD / 32 k-steps
#define NCHK 16          // chunks of 4 k-steps
#define RPB 64           // rows per block
#define NBLK 256         // blocks (1 per CU)
#define DELTA 8e-3f      // argmax gap below which we re-resolve in fp64
#define BUFB 32768       // chunk LDS buffer bytes (hi 16KB + lo 16KB, bf16)
#define FCAP 2048        // flag-list capacity (entries of 132 floats)

typedef __attribute__((ext_vector_type(8))) short  bf16x8;
typedef __attribute__((ext_vector_type(4))) float  f32x4;
typedef __attribute__((ext_vector_type(4))) unsigned int u32x4;

union V16 { u32x4 u; f32x4 f; bf16x8 s; };

// barrier WITHOUT vmcnt drain: LDS ops drained (lgkmcnt), register-destined
// global loads (B fragments, x prefetch) stay in flight across the barrier.
__device__ __forceinline__ void wg_barrier() {
  asm volatile("s_waitcnt lgkmcnt(0)\n\ts_barrier" ::: "memory");
}

// ---------------------------------------------------------------------------
// Prep (coalesced): RNE-round enc_W and dec_W to bf16, laid out in MFMA
// B-fragment order: element ((t*8+ct)*64+l)*8+j <-> W[ct*16+(l&15)][t*32+(l>>4)*8+j].
// 128 blocks = sel(2) x ct(8) x ktile(8); each stages a 16x256 f32 tile via
// LDS (1KB-contiguous reads, contiguous 16B fragment writes).
// Also zeroes the loss/accuracy accumulators and the flag counter.
// ---------------------------------------------------------------------------
__global__ __launch_bounds__(256) void prep_kernel(
    const float* __restrict__ encW, const float* __restrict__ decW,
    unsigned short* __restrict__ wEh, unsigned short* __restrict__ wDh,
    float* __restrict__ out, unsigned int* __restrict__ counter)
{
  __shared__ float sw[16][260];
  const int bid = blockIdx.x;
  const int tid = threadIdx.x;
  if (bid == 0 && tid == 0) { *counter = 0u; out[2*BB] = 0.f; out[2*BB+1] = 0.f; }
  const int sel = bid >> 6, rem = bid & 63;
  const int ct = rem >> 3, kt = rem & 7;
  const float* W = sel ? decW : encW;
  unsigned short* oh = sel ? wDh : wEh;

  {
    const int row = tid >> 4, seg = tid & 15;
    const float* src = W + (size_t)(ct * 16 + row) * DD + kt * 256 + seg * 16;
#pragma unroll
    for (int i = 0; i < 4; ++i)
      *(f32x4*)&sw[row][seg * 16 + i * 4] = *(const f32x4*)(src + i * 4);
  }
  __syncthreads();

  const int l = tid & 63, wv = tid >> 6;
#pragma unroll
  for (int h = 0; h < 2; ++h) {
    const int tt = wv * 2 + h;
    const int t  = kt * 8 + tt;
    const float* sp = &sw[l & 15][tt * 32 + ((l >> 4) << 3)];
    V16 vh;
#pragma unroll
    for (int p = 0; p < 4; ++p) {
      unsigned hu[2];
#pragma unroll
      for (int q = 0; q < 2; ++q) {
        unsigned u  = __float_as_uint(sp[p * 2 + q]);
        unsigned rh = u + 0x7FFFu + ((u >> 16) & 1u);   // RNE to bf16
        hu[q] = (rh >> 16) & 0xFFFFu;
      }
      vh.u[p] = (hu[1] << 16) | hu[0];
    }
    *(u32x4*)(oh + ((size_t)(t * 8 + ct) * 64 + l) * 8) = vh.u;
  }
}

// ---------------------------------------------------------------------------
// Main fused kernel: 256 blocks x 1024 threads (1 block/CU, 16 waves).
// pool=84KB forces 1 block/CU occupancy -> RA VGPR budget 128 -> the ~90-reg
// live set (8 B-frags x2 sets + 4 acc + staging) fits with NO SPILLS (the
// round-6 64-VGPR spill disease removed).
// Wave w: wr = w&3 (16-row group), wcg = w>>2 (32-col group, 2 MFMA col-tiles).
// x split to bf16 hi/lo ONCE at stage time into swizzled LDS planes; B frags
// global->VGPR (L1-reused by the 4 row-group waves). Per wave/k-step:
// 2 ds_read_b128 + 4 B loads + 6 MFMA (enc 2-term: ah*Eh + al*Eh; dec: ah*Dh).
// 4 k-steps per barrier; barrier does NOT drain vmcnt (prefetch flows across).
// Epilogue additionally dumps the full approx s-row for flagged rows.
// ---------------------------------------------------------------------------
__global__ __launch_bounds__(1024)
void main_kernel(
    const float* __restrict__ x, const float* __restrict__ y,
    const float* __restrict__ encb, const float* __restrict__ decb,
    const unsigned short* __restrict__ wEh, const unsigned short* __restrict__ wDh,
    float* __restrict__ out, unsigned int* __restrict__ counter,
    float* __restrict__ list)
{
  __shared__ __align__(16) unsigned char pool[86016];   // 1 block/CU -> 128-reg budget
  const int tid = threadIdx.x;
  const int w = tid >> 6, l = tid & 63;
  const int wr = w & 3, wcg = w >> 2;
  const int rbase = blockIdx.x * RPB;

  // stage addressing: thread -> (row srow, 16B seg); 8 consecutive floats
  const int srow = tid >> 4, seg = tid & 15;
  const float* gXc = x + (size_t)(rbase + srow) * DD + seg * 8;
  const int woff = srow * 256 + ((seg ^ (srow & 15)) << 4);

  // B fragment sources (direct to regs); wave covers tiles wcg*2, wcg*2+1
  const unsigned short* gE = wEh + (size_t)(wcg * 1024 + l * 8);
  const unsigned short* gD = wDh + (size_t)(wcg * 1024 + l * 8);

  // A-fragment LDS byte offsets
  const int rowb = (wr * 16 + (l & 15)) * 256;
  int blkb[4];
#pragma unroll
  for (int tt = 0; tt < 4; ++tt)
    blkb[tt] = ((tt * 4 + (l >> 4)) ^ (l & 15)) << 4;

  f32x4 accE[2], accD[2];
  const f32x4 zero4 = {0.f, 0.f, 0.f, 0.f};
#pragma unroll
  for (int c = 0; c < 2; ++c) { accE[c] = zero4; accD[c] = zero4; }

  auto WRX = [&](int nb, f32x4 A, f32x4 Bv) {
    float fa[8] = {A[0],A[1],A[2],A[3],Bv[0],Bv[1],Bv[2],Bv[3]};
    V16 vh, vl;
#pragma unroll
    for (int p = 0; p < 4; ++p) {
      unsigned u0 = __float_as_uint(fa[2*p]);
      unsigned u1 = __float_as_uint(fa[2*p+1]);
      vh.u[p] = (u0 >> 16) | (u1 & 0xFFFF0000u);
      float r0 = fa[2*p]   - __uint_as_float(u0 & 0xFFFF0000u);
      float r1 = fa[2*p+1] - __uint_as_float(u1 & 0xFFFF0000u);
      vl.u[p] = (__float_as_uint(r0) >> 16) | (__float_as_uint(r1) & 0xFFFF0000u);
    }
    unsigned char* bp = pool + nb + woff;
    *(u32x4*)bp            = vh.u;
    *(u32x4*)(bp + 16384)  = vl.u;
  };

#define LDB(base, t, off) (*(const bf16x8*)((base) + (size_t)(t) * 4096 + (off)))
#define LDBH(h, e0, e1, d0, d1, f0, f1, g0, g1) do {                 \
    int _t = (h) * 2;                                                \
    e0 = LDB(gE, _t, 0);     e1 = LDB(gE, _t, 512);                  \
    d0 = LDB(gD, _t, 0);     d1 = LDB(gD, _t, 512);                  \
    f0 = LDB(gE, _t + 1, 0); f1 = LDB(gE, _t + 1, 512);              \
    g0 = LDB(gD, _t + 1, 0); g1 = LDB(gD, _t + 1, 512);              \
  } while (0)

#define MFMA(a, b, c) __builtin_amdgcn_mfma_f32_16x16x32_bf16(a, b, c, 0, 0, 0)
#define KSTEP(cbase, tt, E0, E1, D0, D1) do {                                    \
    const unsigned char* ap = pool + (cbase) + rowb + blkb[tt];                  \
    bf16x8 ah = *(const bf16x8*)ap;                                              \
    bf16x8 al = *(const bf16x8*)(ap + 16384);                                    \
    accE[0] = MFMA(ah, E0, accE[0]);                                             \
    accE[1] = MFMA(ah, E1, accE[1]);                                             \
    accD[0] = MFMA(ah, D0, accD[0]);                                             \
    accD[1] = MFMA(ah, D1, accD[1]);                                             \
    accE[0] = MFMA(al, E0, accE[0]);                                             \
    accE[1] = MFMA(al, E1, accE[1]);                                             \
  } while (0)

  bf16x8 Se0,Se1,Sd0,Sd1, Sf0,Sf1,Sg0,Sg1;   // ksteps 4c, 4c+1
  bf16x8 Te0,Te1,Td0,Td1, Tf0,Tf1,Tg0,Tg1;   // ksteps 4c+2, 4c+3
  f32x4 xA, xB;

  // prologue: chunk 0 x -> buffer 0; B ksteps 0,1 -> S
  xA = *(const f32x4*)gXc; xB = *(const f32x4*)(gXc + 4);
  LDBH(0, Se0,Se1,Sd0,Sd1, Sf0,Sf1,Sg0,Sg1);
  WRX(0, xA, xB);
  wg_barrier();

  for (int c = 0; c < NCHK; ++c) {
    const int cb = (c & 1) * BUFB;
    const int nb = cb ^ BUFB;
    LDBH(2 * c + 1, Te0,Te1,Td0,Td1, Tf0,Tf1,Tg0,Tg1);
    if (c + 1 < NCHK) {
      const float* p = gXc + (size_t)(c + 1) * 128;
      xA = *(const f32x4*)p; xB = *(const f32x4*)(p + 4);
    }
    __builtin_amdgcn_s_setprio(1);
    KSTEP(cb, 0, Se0, Se1, Sd0, Sd1);
    KSTEP(cb, 1, Sf0, Sf1, Sg0, Sg1);
    __builtin_amdgcn_s_setprio(0);
    if (c + 1 < NCHK)
      LDBH(2 * c + 2, Se0,Se1,Sd0,Sd1, Sf0,Sf1,Sg0,Sg1);
    __builtin_amdgcn_s_setprio(1);
    KSTEP(cb, 2, Te0, Te1, Td0, Td1);
    KSTEP(cb, 3, Tf0, Tf1, Tg0, Tg1);
    __builtin_amdgcn_s_setprio(0);
    if (c + 1 < NCHK) WRX(nb, xA, xB);   // x latency hidden by this chunk
    wg_barrier();
  }
#undef LDBH
#undef KSTEP
#undef LDB
#undef MFMA

  // ---------------- epilogue (overlays the staging pool) ----------------
  float* sT  = (float*)pool;                  // [64][132] dec-GEMM results
  float* sS  = (float*)(pool + 33792);        // [64][128] enc s-values (biased)
  float* sm1 = (float*)(pool + 66560);        // [64][4] top-1
  float* sm2 = (float*)(pool + 67584);        // [64][4] top-2
  int*   si1 = (int*)  (pool + 68608);        // [64][4] argmax col

  {
    const int q = l >> 4, cc = l & 15;
    const int col0 = wcg * 32 + cc;
    const int col1 = col0 + 16;
#pragma unroll
    for (int c = 0; c < 2; ++c) {
      const int col = wcg * 32 + c * 16 + cc;
#pragma unroll
      for (int i = 0; i < 4; ++i)
        sT[(wr * 16 + q * 4 + i) * 132 + col] = accD[c][i];
    }
    const float b0 = encb[col0], b1 = encb[col1];
    float m1v[4], m2v[4]; int i1v[4];
#pragma unroll
    for (int i = 0; i < 4; ++i) {
      const int row = wr * 16 + q * 4 + i;
      float v0 = accE[0][i] + b0;
      float v1 = accE[1][i] + b1;
      sS[row * 128 + col0] = v0;
      sS[row * 128 + col1] = v1;
      if (v0 >= v1) { m1v[i] = v0; m2v[i] = v1; i1v[i] = col0; }
      else          { m1v[i] = v1; m2v[i] = v0; i1v[i] = col1; }
    }
#pragma unroll
    for (int d = 1; d < 16; d <<= 1) {
#pragma unroll
      for (int i = 0; i < 4; ++i) {
        float om1 = __shfl_xor(m1v[i], d);
        float om2 = __shfl_xor(m2v[i], d);
        int   oi  = __shfl_xor(i1v[i], d);
        if (om1 > m1v[i] || (om1 == m1v[i] && oi < i1v[i])) {
          m2v[i] = fmaxf(m1v[i], om2); m1v[i] = om1; i1v[i] = oi;
        } else {
          m2v[i] = fmaxf(m2v[i], om1);
        }
      }
    }
    if (cc == 0) {
#pragma unroll
      for (int i = 0; i < 4; ++i) {
        const int row = wr * 16 + q * 4 + i;
        sm1[row * 4 + wcg] = m1v[i];
        sm2[row * 4 + wcg] = m2v[i];
        si1[row * 4 + wcg] = i1v[i];
      }
    }
  }
  __syncthreads();

  float lossAcc = 0.f, accAcc = 0.f;
  if (tid < RPB) {
    const int row = tid, R = rbase + row;
    float m1 = -3.4e38f, m2 = -3.4e38f; int i1 = 0;
#pragma unroll
    for (int g = 0; g < 4; ++g) {
      float a1 = sm1[row * 4 + g], a2 = sm2[row * 4 + g];
      int ai = si1[row * 4 + g];
      if (a1 > m1) { m2 = fmaxf(m1, a2); m1 = a1; i1 = ai; }
      else         { m2 = fmaxf(m2, a1); }
    }
    float yh = sT[row * 132 + i1] + decb[i1];
    out[R]      = yh;
    out[BB + R] = (float)i1;
    if (m1 - m2 < DELTA) {                     // near-tie: fp64 re-resolve later
      unsigned p = atomicAdd(counter, 1u);
      if (p < (unsigned)FCAP) {
        float* ent = list + (size_t)p * 132;
        ((unsigned*)ent)[0] = (unsigned)R;
        const f32x4* sr = (const f32x4*)(sS + row * 128);
        f32x4* dst = (f32x4*)(ent + 4);
#pragma unroll
        for (int j = 0; j < 32; ++j) dst[j] = sr[j];
      }
    }
    float yv = y[R];
    float d  = yh - yv;
    lossAcc = d * d;
    float sg = (yh > 0.f) ? 1.f : ((yh < 0.f) ? -1.f : 0.f);
    accAcc = (sg == yv) ? 1.f : 0.f;
  }
#pragma unroll
  for (int d = 1; d < 64; d <<= 1) {
    lossAcc += __shfl_xor(lossAcc, d);
    accAcc  += __shfl_xor(accAcc, d);
  }
  if (tid == 0) {
    atomicAdd(&out[2*BB],     lossAcc * (1.f / BB));
    atomicAdd(&out[2*BB + 1], accAcc  * (1.f / BB));
  }
}

// ---------------------------------------------------------------------------
// Fixup v2: one wave per flagged row. Reads the dumped approx s-row, selects
// candidate cols within (m1 - 2*DELTA), recomputes ONLY those (typically 1-3)
// in fp64 (coalesced 1KB loads), picks the true argmax, recomputes y_hat in
// fp64, patches out + loss/accuracy atomics.
// ---------------------------------------------------------------------------
__global__ __launch_bounds__(64) void fixup_kernel(
    const float* __restrict__ x, const float* __restrict__ y,
    const float* __restrict__ encW, const float* __restrict__ encb,
    const float* __restrict__ decW, const float* __restrict__ decb,
    float* __restrict__ out,
    const unsigned int* __restrict__ counter, const float* __restrict__ list)
{
  int n = (int)*counter;
  if (n > FCAP) n = FCAP;
  const int l = threadIdx.x;
  for (int e = blockIdx.x; e < n; e += gridDim.x) {
    const float* ent = list + (size_t)e * 132;
    const int R = (int)((const unsigned*)ent)[0];
    const float s0 = ent[4 + 2 * l], s1 = ent[5 + 2 * l];
    float m = fmaxf(s0, s1);
#pragma unroll
    for (int d = 1; d < 64; d <<= 1) m = fmaxf(m, __shfl_xor(m, d));
    const float win = m - 2.0f * DELTA;
    unsigned long long mm0 = __ballot(s0 >= win);
    unsigned long long mm1 = __ballot(s1 >= win);
    const float* xr = x + (size_t)R * DD;
    double best = -1e300; int bk = KK;
    while (mm0 | mm1) {
      int c;
      if (mm0) { int b = __builtin_ctzll(mm0); mm0 &= mm0 - 1; c = 2 * b; }
      else     { int b = __builtin_ctzll(mm1); mm1 &= mm1 - 1; c = 2 * b + 1; }
      const float* wp = encW + (size_t)c * DD;
      double s = 0.0;
#pragma unroll
      for (int j = 0; j < 8; ++j) {
        f32x4 wv = *(const f32x4*)(wp + j * 256 + l * 4);
        f32x4 xv = *(const f32x4*)(xr + j * 256 + l * 4);
        s = fma((double)xv[0], (double)wv[0], s);
        s = fma((double)xv[1], (double)wv[1], s);
        s = fma((double)xv[2], (double)wv[2], s);
        s = fma((double)xv[3], (double)wv[3], s);
      }
#pragma unroll
      for (int d = 1; d < 64; d <<= 1) s += __shfl_xor(s, d);
      s += (double)encb[c];
      if (s > best || (s == best && c < bk)) { best = s; bk = c; }
    }
    // dec dot in fp64
    const float* dr = decW + (size_t)bk * DD;
    double t = 0.0;
#pragma unroll
    for (int j = 0; j < 8; ++j) {
      f32x4 wv = *(const f32x4*)(dr + j * 256 + l * 4);
      f32x4 xv = *(const f32x4*)(xr + j * 256 + l * 4);
      t = fma((double)xv[0], (double)wv[0], t);
      t = fma((double)xv[1], (double)wv[1], t);
      t = fma((double)xv[2], (double)wv[2], t);
      t = fma((double)xv[3], (double)wv[3], t);
    }
#pragma unroll
    for (int d = 1; d < 64; d <<= 1) t += __shfl_xor(t, d);
    if (l == 0) {
      float yh = (float)(t + (double)decb[bk]);
      float yv = y[R];
      float old = out[R];
      float dn = yh - yv, dol = old - yv;
      atomicAdd(&out[2*BB], (dn*dn - dol*dol) * (1.f / BB));
      float sgn = (yh  > 0.f) ? 1.f : ((yh  < 0.f) ? -1.f : 0.f);
      float sgo = (old > 0.f) ? 1.f : ((old < 0.f) ? -1.f : 0.f);
      float mn = (sgn == yv) ? 1.f : 0.f;
      float mo = (sgo == yv) ? 1.f : 0.f;
      atomicAdd(&out[2*BB + 1], (mn - mo) * (1.f / BB));
      out[R]      = yh;
      out[BB + R] = (float)bk;
    }
  }
}

extern "C" void kernel_launch(void* const* d_in, const int* in_sizes, int n_in,
                              void* d_out, int out_size, void* d_ws, size_t ws_size,
                              hipStream_t stream)
{
  const float* x    = (const float*)d_in[0];
  const float* y    = (const float*)d_in[1];
  // d_in[2] = z (unused by the reference computation)
  const float* encW = (const float*)d_in[3];
  const float* encb = (const float*)d_in[4];
  const float* decW = (const float*)d_in[5];   // [1,128,2048] -> row-major [128][2048]
  const float* decb = (const float*)d_in[6];
  float* out = (float*)d_out;

  unsigned char* ws = (unsigned char*)d_ws;
  unsigned short* wEh = (unsigned short*)ws;                 // 512 KB
  unsigned short* wDh = (unsigned short*)(ws + 524288);      // 512 KB
  unsigned int* counter = (unsigned int*)(ws + 1048576);
  float* list = (float*)(ws + 1048592);                      // FCAP x 132 floats

  prep_kernel<<<128, 256, 0, stream>>>(encW, decW, wEh, wDh, out, counter);
  main_kernel<<<NBLK, 1024, 0, stream>>>(x, y, encb, decb, wEh, wDh,
                                         out, counter, list);
  fixup_kernel<<<512, 64, 0, stream>>>(x, y, encW, encb, decW, decb,
                                       out, counter, list);
}

// Round 12
// 83.761 us; speedup vs baseline: 2.0071x; 1.0203x over previous
//
#include <hip/hip_runtime.h>

// Problem constants (reference: B=16384, DIM_X=2048, K=128)
#define BB 16384
#define DD 2048
#define KK 128
#define NT 64            // DD / 32 k-steps
#define NCHK 32          // chunks of 2 k-steps
#define RPB 64           // rows per block
#define NBLK 256         // blocks (1 per CU)
#define DELTA 8e-3f      // argmax gap below which we re-resolve in fp64
#define BUFS 49152       // per-chunk buffer: xhi 8K | xlo 8K | E 16K | D 16K
#define FCAP 2048        // flag-list capacity (entries of 132 floats)

typedef __attribute__((ext_vector_type(8))) short  bf16x8;
typedef __attribute__((ext_vector_type(4))) float  f32x4;
typedef __attribute__((ext_vector_type(4))) unsigned int u32x4;

union V16 { u32x4 u; f32x4 f; bf16x8 s; };

__device__ __forceinline__ void gld16(const void* g, void* l) {
  __builtin_amdgcn_global_load_lds(
      (const __attribute__((address_space(1))) void*)g,
      (__attribute__((address_space(3))) void*)l, 16, 0, 0);
}

// ---------------------------------------------------------------------------
// Prep (coalesced): RNE-round enc_W and dec_W to bf16, laid out in MFMA
// B-fragment order: element ((t*8+ct)*64+l)*8+j <-> W[ct*16+(l&15)][t*32+(l>>4)*8+j].
// 128 blocks = sel(2) x ct(8) x ktile(8); each stages a 16x256 f32 tile via
// LDS (1KB-contiguous reads, contiguous 16B fragment writes).
// Also zeroes the loss/accuracy accumulators and the flag counter.
// ---------------------------------------------------------------------------
__global__ __launch_bounds__(256) void prep_kernel(
    const float* __restrict__ encW, const float* __restrict__ decW,
    unsigned short* __restrict__ wEh, unsigned short* __restrict__ wDh,
    float* __restrict__ out, unsigned int* __restrict__ counter)
{
  __shared__ float sw[16][260];
  const int bid = blockIdx.x;
  const int tid = threadIdx.x;
  if (bid == 0 && tid == 0) { *counter = 0u; out[2*BB] = 0.f; out[2*BB+1] = 0.f; }
  const int sel = bid >> 6, rem = bid & 63;
  const int ct = rem >> 3, kt = rem & 7;
  const float* W = sel ? decW : encW;
  unsigned short* oh = sel ? wDh : wEh;

  {
    const int row = tid >> 4, seg = tid & 15;
    const float* src = W + (size_t)(ct * 16 + row) * DD + kt * 256 + seg * 16;
#pragma unroll
    for (int i = 0; i < 4; ++i)
      *(f32x4*)&sw[row][seg * 16 + i * 4] = *(const f32x4*)(src + i * 4);
  }
  __syncthreads();

  const int l = tid & 63, wv = tid >> 6;
#pragma unroll
  for (int h = 0; h < 2; ++h) {
    const int tt = wv * 2 + h;
    const int t  = kt * 8 + tt;
    const float* sp = &sw[l & 15][tt * 32 + ((l >> 4) << 3)];
    V16 vh;
#pragma unroll
    for (int p = 0; p < 4; ++p) {
      unsigned hu[2];
#pragma unroll
      for (int q = 0; q < 2; ++q) {
        unsigned u  = __float_as_uint(sp[p * 2 + q]);
        unsigned rh = u + 0x7FFFu + ((u >> 16) & 1u);   // RNE to bf16
        hu[q] = (rh >> 16) & 0xFFFFu;
      }
      vh.u[p] = (hu[1] << 16) | hu[0];
    }
    *(u32x4*)(oh + ((size_t)(t * 8 + ct) * 64 + l) * 8) = vh.u;
  }
}

// ---------------------------------------------------------------------------
// Main fused kernel: 256 blocks x 512 threads (1 block/CU, 8 waves).
// Minimal-traffic decomposition: wave w = (wr = w>>2) in 2 row-groups x
// (wcg = w&3) in 4 col-groups; rt=2 (rows wr*32..+31), ct=2 (cols wcg*32..+31).
// Per-kstep operand traffic/CU = A(8KB)x4 + B(16KB)x2 = 64KB, ALL through LDS
// (vs round 11's 64KB B through L1 with 4x redundancy -- the 27us floor).
// B staged per-chunk via global_load_lds DMA (single shared copy, contiguous
// 1KB frags, dense conflict-free reads). x split to bf16 hi/lo at stage into
// XOR-swizzled planes. Chunk = 2 ksteps, double-buffered 48KB buffers (96KB
// LDS -> 1 block/CU -> 2 waves/SIMD -> 256-VGPR RA budget, no spills).
// Per wave/kstep: 4 A ds_read + 4 B ds_read + 12 MFMA.
// ---------------------------------------------------------------------------
__global__ __launch_bounds__(512)
void main_kernel(
    const float* __restrict__ x, const float* __restrict__ y,
    const float* __restrict__ encb, const float* __restrict__ decb,
    const unsigned short* __restrict__ wEh, const unsigned short* __restrict__ wDh,
    float* __restrict__ out, unsigned int* __restrict__ counter,
    float* __restrict__ list)
{
  __shared__ __align__(16) unsigned char pool[98304];
  const int tid = threadIdx.x;
  const int w = tid >> 6, l = tid & 63;
  const int wr = w >> 2, wcg = w & 3;
  const int rbase = blockIdx.x * RPB;

  // x stage addressing: thread -> (row srow, 16B seg of 8 floats)
  const int srow = tid >> 3, seg = tid & 7;
  const float* gXc = x + (size_t)(rbase + srow) * DD + seg * 8;
  const int woff = srow * 128 + ((seg ^ (srow & 7)) << 4);   // hi-plane byte off

  // A-fragment LDS offsets
  int rowb[2];
#pragma unroll
  for (int rt = 0; rt < 2; ++rt)
    rowb[rt] = (wr * 32 + rt * 16 + (l & 15)) * 128;
  int blkb[2];
#pragma unroll
  for (int tt = 0; tt < 2; ++tt)
    blkb[tt] = ((tt * 4 + (l >> 4)) ^ (l & 7)) << 4;

  // B-fragment LDS offset (within E or D plane of a kstep): dense 1KB frags
  const int bfo = wcg * 2048 + (l << 4);

  f32x4 accE[2][2], accD[2][2];
  const f32x4 zero4 = {0.f, 0.f, 0.f, 0.f};
#pragma unroll
  for (int rt = 0; rt < 2; ++rt)
#pragma unroll
    for (int ct = 0; ct < 2; ++ct) { accE[rt][ct] = zero4; accD[rt][ct] = zero4; }

  auto WRX = [&](int nb, f32x4 A, f32x4 Bv) {
    float fa[8] = {A[0],A[1],A[2],A[3],Bv[0],Bv[1],Bv[2],Bv[3]};
    V16 vh, vl;
#pragma unroll
    for (int p = 0; p < 4; ++p) {
      unsigned u0 = __float_as_uint(fa[2*p]);
      unsigned u1 = __float_as_uint(fa[2*p+1]);
      vh.u[p] = (u0 >> 16) | (u1 & 0xFFFF0000u);
      float r0 = fa[2*p]   - __uint_as_float(u0 & 0xFFFF0000u);
      float r1 = fa[2*p+1] - __uint_as_float(u1 & 0xFFFF0000u);
      vl.u[p] = (__float_as_uint(r0) >> 16) | (__float_as_uint(r1) & 0xFFFF0000u);
    }
    unsigned char* bp = pool + nb + woff;
    *(u32x4*)bp           = vh.u;
    *(u32x4*)(bp + 8192)  = vl.u;
  };

  // B DMA: 4 gld16/thread/chunk -> E(kstep0), E(kstep1), D(k0), D(k1)
  auto DMAB = [&](int nb, int c) {
    const unsigned short* eb = wEh + (size_t)(2 * c) * 4096 + tid * 8;
    const unsigned short* db = wDh + (size_t)(2 * c) * 4096 + tid * 8;
    gld16(eb,        pool + nb + 16384 + w * 1024);
    gld16(eb + 4096, pool + nb + 24576 + w * 1024);
    gld16(db,        pool + nb + 32768 + w * 1024);
    gld16(db + 4096, pool + nb + 40960 + w * 1024);
  };

#define MFMA(a, b, c) __builtin_amdgcn_mfma_f32_16x16x32_bf16(a, b, c, 0, 0, 0)
#define KSTEP(cbase, tt) do {                                                    \
    const unsigned char* bp = pool + (cbase);                                    \
    const unsigned char* bb = bp + 16384 + (tt) * 8192 + bfo;                    \
    bf16x8 E0 = *(const bf16x8*)bb;                                              \
    bf16x8 E1 = *(const bf16x8*)(bb + 1024);                                     \
    bf16x8 D0 = *(const bf16x8*)(bb + 16384);                                    \
    bf16x8 D1 = *(const bf16x8*)(bb + 16384 + 1024);                             \
    _Pragma("unroll")                                                            \
    for (int rt = 0; rt < 2; ++rt) {                                             \
      const unsigned char* ap = bp + rowb[rt] + blkb[tt];                        \
      bf16x8 ah = *(const bf16x8*)ap;                                            \
      bf16x8 al = *(const bf16x8*)(ap + 8192);                                   \
      accE[rt][0] = MFMA(ah, E0, accE[rt][0]);                                   \
      accE[rt][1] = MFMA(ah, E1, accE[rt][1]);                                   \
      accD[rt][0] = MFMA(ah, D0, accD[rt][0]);                                   \
      accD[rt][1] = MFMA(ah, D1, accD[rt][1]);                                   \
      accE[rt][0] = MFMA(al, E0, accE[rt][0]);                                   \
      accE[rt][1] = MFMA(al, E1, accE[rt][1]);                                   \
    }                                                                            \
  } while (0)

  // prologue: chunk 0 -> buffer 0
  {
    f32x4 xA = *(const f32x4*)gXc;
    f32x4 xB = *(const f32x4*)(gXc + 4);
    DMAB(0, 0);
    WRX(0, xA, xB);
    asm volatile("s_waitcnt vmcnt(0) lgkmcnt(0)" ::: "memory");
    __builtin_amdgcn_s_barrier();
  }

  for (int c = 0; c < NCHK; ++c) {
    const int cb = (c & 1) * BUFS;
    const int nb = cb ^ BUFS;
    f32x4 xA, xB;
    if (c + 1 < NCHK) {
      const float* p = gXc + (size_t)(c + 1) * 64;
      xA = *(const f32x4*)p; xB = *(const f32x4*)(p + 4);
      DMAB(nb, c + 1);                      // DMA issued early, retires under compute
    }
    __builtin_amdgcn_s_setprio(1);
    KSTEP(cb, 0);
    KSTEP(cb, 1);
    __builtin_amdgcn_s_setprio(0);
    if (c + 1 < NCHK) WRX(nb, xA, xB);      // x latency hidden by this chunk
    asm volatile("s_waitcnt vmcnt(0) lgkmcnt(0)" ::: "memory");
    __builtin_amdgcn_s_barrier();
  }
#undef KSTEP
#undef MFMA

  // ---------------- epilogue (overlays the staging pool) ----------------
  float* sT  = (float*)pool;                  // [64][132] dec-GEMM results
  float* sS  = (float*)(pool + 33792);        // [64][128] enc s-values (biased)
  float* sm1 = (float*)(pool + 66560);        // [64][4] top-1
  float* sm2 = (float*)(pool + 67584);        // [64][4] top-2
  int*   si1 = (int*)  (pool + 68608);        // [64][4] argmax col

  {
    const int q = l >> 4, cc = l & 15;
    const int col0 = wcg * 32 + cc;
    const int col1 = col0 + 16;
#pragma unroll
    for (int rt = 0; rt < 2; ++rt)
#pragma unroll
      for (int ct = 0; ct < 2; ++ct) {
        const int col = wcg * 32 + ct * 16 + cc;
#pragma unroll
        for (int i = 0; i < 4; ++i)
          sT[(wr * 32 + rt * 16 + q * 4 + i) * 132 + col] = accD[rt][ct][i];
      }
    const float b0 = encb[col0], b1 = encb[col1];
    float m1v[8], m2v[8]; int i1v[8];
#pragma unroll
    for (int rt = 0; rt < 2; ++rt)
#pragma unroll
      for (int i = 0; i < 4; ++i) {
        const int j = rt * 4 + i;
        const int row = wr * 32 + rt * 16 + q * 4 + i;
        float v0 = accE[rt][0][i] + b0;
        float v1 = accE[rt][1][i] + b1;
        sS[row * 128 + col0] = v0;
        sS[row * 128 + col1] = v1;
        if (v0 >= v1) { m1v[j] = v0; m2v[j] = v1; i1v[j] = col0; }
        else          { m1v[j] = v1; m2v[j] = v0; i1v[j] = col1; }
      }
#pragma unroll
    for (int d = 1; d < 16; d <<= 1) {
#pragma unroll
      for (int j = 0; j < 8; ++j) {
        float om1 = __shfl_xor(m1v[j], d);
        float om2 = __shfl_xor(m2v[j], d);
        int   oi  = __shfl_xor(i1v[j], d);
        if (om1 > m1v[j] || (om1 == m1v[j] && oi < i1v[j])) {
          m2v[j] = fmaxf(m1v[j], om2); m1v[j] = om1; i1v[j] = oi;
        } else {
          m2v[j] = fmaxf(m2v[j], om1);
        }
      }
    }
    if (cc == 0) {
#pragma unroll
      for (int rt = 0; rt < 2; ++rt)
#pragma unroll
        for (int i = 0; i < 4; ++i) {
          const int j = rt * 4 + i;
          const int row = wr * 32 + rt * 16 + q * 4 + i;
          sm1[row * 4 + wcg] = m1v[j];
          sm2[row * 4 + wcg] = m2v[j];
          si1[row * 4 + wcg] = i1v[j];
        }
    }
  }
  __syncthreads();

  float lossAcc = 0.f, accAcc = 0.f;
  if (tid < RPB) {
    const int row = tid, R = rbase + row;
    float m1 = -3.4e38f, m2 = -3.4e38f; int i1 = 0;
#pragma unroll
    for (int g = 0; g < 4; ++g) {
      float a1 = sm1[row * 4 + g], a2 = sm2[row * 4 + g];
      int ai = si1[row * 4 + g];
      if (a1 > m1) { m2 = fmaxf(m1, a2); m1 = a1; i1 = ai; }
      else         { m2 = fmaxf(m2, a1); }
    }
    float yh = sT[row * 132 + i1] + decb[i1];
    out[R]      = yh;
    out[BB + R] = (float)i1;
    if (m1 - m2 < DELTA) {                     // near-tie: fp64 re-resolve later
      unsigned p = atomicAdd(counter, 1u);
      if (p < (unsigned)FCAP) {
        float* ent = list + (size_t)p * 132;
        ((unsigned*)ent)[0] = (unsigned)R;
        const f32x4* sr = (const f32x4*)(sS + row * 128);
        f32x4* dst = (f32x4*)(ent + 4);
#pragma unroll
        for (int j = 0; j < 32; ++j) dst[j] = sr[j];
      }
    }
    float yv = y[R];
    float d  = yh - yv;
    lossAcc = d * d;
    float sg = (yh > 0.f) ? 1.f : ((yh < 0.f) ? -1.f : 0.f);
    accAcc = (sg == yv) ? 1.f : 0.f;
  }
#pragma unroll
  for (int d = 1; d < 64; d <<= 1) {
    lossAcc += __shfl_xor(lossAcc, d);
    accAcc  += __shfl_xor(accAcc, d);
  }
  if (tid == 0) {
    atomicAdd(&out[2*BB],     lossAcc * (1.f / BB));
    atomicAdd(&out[2*BB + 1], accAcc  * (1.f / BB));
  }
}

// ---------------------------------------------------------------------------
// Fixup v2: one wave per flagged row. Reads the dumped approx s-row, selects
// candidate cols within (m1 - 2*DELTA), recomputes ONLY those (typically 1-3)
// in fp64 (coalesced 1KB loads), picks the true argmax, recomputes y_hat in
// fp64, patches out + loss/accuracy atomics.
// ---------------------------------------------------------------------------
__global__ __launch_bounds__(64) void fixup_kernel(
    const float* __restrict__ x, const float* __restrict__ y,
    const float* __restrict__ encW, const float* __restrict__ encb,
    const float* __restrict__ decW, const float* __restrict__ decb,
    float* __restrict__ out,
    const unsigned int* __restrict__ counter, const float* __restrict__ list)
{
  int n = (int)*counter;
  if (n > FCAP) n = FCAP;
  const int l = threadIdx.x;
  for (int e = blockIdx.x; e < n; e += gridDim.x) {
    const float* ent = list + (size_t)e * 132;
    const int R = (int)((const unsigned*)ent)[0];
    const float s0 = ent[4 + 2 * l], s1 = ent[5 + 2 * l];
    float m = fmaxf(s0, s1);
#pragma unroll
    for (int d = 1; d < 64; d <<= 1) m = fmaxf(m, __shfl_xor(m, d));
    const float win = m - 2.0f * DELTA;
    unsigned long long mm0 = __ballot(s0 >= win);
    unsigned long long mm1 = __ballot(s1 >= win);
    const float* xr = x + (size_t)R * DD;
    double best = -1e300; int bk = KK;
    while (mm0 | mm1) {
      int c;
      if (mm0) { int b = __builtin_ctzll(mm0); mm0 &= mm0 - 1; c = 2 * b; }
      else     { int b = __builtin_ctzll(mm1); mm1 &= mm1 - 1; c = 2 * b + 1; }
      const float* wp = encW + (size_t)c * DD;
      double s = 0.0;
#pragma unroll
      for (int j = 0; j < 8; ++j) {
        f32x4 wv = *(const f32x4*)(wp + j * 256 + l * 4);
        f32x4 xv = *(const f32x4*)(xr + j * 256 + l * 4);
        s = fma((double)xv[0], (double)wv[0], s);
        s = fma((double)xv[1], (double)wv[1], s);
        s = fma((double)xv[2], (double)wv[2], s);
        s = fma((double)xv[3], (double)wv[3], s);
      }
#pragma unroll
      for (int d = 1; d < 64; d <<= 1) s += __shfl_xor(s, d);
      s += (double)encb[c];
      if (s > best || (s == best && c < bk)) { best = s; bk = c; }
    }
    // dec dot in fp64
    const float* dr = decW + (size_t)bk * DD;
    double t = 0.0;
#pragma unroll
    for (int j = 0; j < 8; ++j) {
      f32x4 wv = *(const f32x4*)(dr + j * 256 + l * 4);
      f32x4 xv = *(const f32x4*)(xr + j * 256 + l * 4);
      t = fma((double)xv[0], (double)wv[0], t);
      t = fma((double)xv[1], (double)wv[1], t);
      t = fma((double)xv[2], (double)wv[2], t);
      t = fma((double)xv[3], (double)wv[3], t);
    }
#pragma unroll
    for (int d = 1; d < 64; d <<= 1) t += __shfl_xor(t, d);
    if (l == 0) {
      float yh = (float)(t + (double)decb[bk]);
      float yv = y[R];
      float old = out[R];
      float dn = yh - yv, dol = old - yv;
      atomicAdd(&out[2*BB], (dn*dn - dol*dol) * (1.f / BB));
      float sgn = (yh  > 0.f) ? 1.f : ((yh  < 0.f) ? -1.f : 0.f);
      float sgo = (old > 0.f) ? 1.f : ((old < 0.f) ? -1.f : 0.f);
      float mn = (sgn == yv) ? 1.f : 0.f;
      float mo = (sgo == yv) ? 1.f : 0.f;
      atomicAdd(&out[2*BB + 1], (mn - mo) * (1.f / BB));
      out[R]      = yh;
      out[BB + R] = (float)bk;
    }
  }
}

extern "C" void kernel_launch(void* const* d_in, const int* in_sizes, int n_in,
                              void* d_out, int out_size, void* d_ws, size_t ws_size,
                              hipStream_t stream)
{
  const float* x    = (const float*)d_in[0];
  const float* y    = (const float*)d_in[1];
  // d_in[2] = z (unused by the reference computation)
  const float* encW = (const float*)d_in[3];
  const float* encb = (const float*)d_in[4];
  const float* decW = (const float*)d_in[5];   // [1,128,2048] -> row-major [128][2048]
  const float* decb = (const float*)d_in[6];
  float* out = (float*)d_out;

  unsigned char* ws = (unsigned char*)d_ws;
  unsigned short* wEh = (unsigned short*)ws;                 // 512 KB
  unsigned short* wDh = (unsigned short*)(ws + 524288);      // 512 KB
  unsigned int* counter = (unsigned int*)(ws + 1048576);
  float* list = (float*)(ws + 1048592);                      // FCAP x 132 floats

  prep_kernel<<<128, 256, 0, stream>>>(encW, decW, wEh, wDh, out, counter);
  main_kernel<<<NBLK, 512, 0, stream>>>(x, y, encb, decb, wEh, wDh,
                                        out, counter, list);
  fixup_kernel<<<512, 64, 0, stream>>>(x, y, encW, encb, decW, decb,
                                       out, counter, list);
}